// Round 12
// baseline (35.782 us; speedup 1.0000x reference)
//
#include <hip/hip_runtime.h>
#include <float.h>

#define BATCH 32
#define NP 512
#define NG 512
#define TSTEP 10
#define NI (NG * TSTEP)                   // 5120 candidates per batch
#define NPAIR_B (NI / 2)                  // 2560 pairs per batch
#define NCHUNK 16                         // chunks per batch
#define CH_PAIRS (NPAIR_B / NCHUNK)       // 160 pairs per chunk
#define TILE_CANDS 16
#define TILE_PAIRS 8
#define TILES_CH (CH_PAIRS / TILE_PAIRS)  // 20 tiles per chunk
#define NB_SCAN (BATCH * NCHUNK)          // 512
#define NB_G2P 64                         // 2 blocks/batch
#define THR 256
#define RPT 2                             // preds per thread (RPT*256 = NP)
#define NPRED (BATCH * NP)                // 16384

typedef float f2 __attribute__((ext_vector_type(2)));
typedef float f4 __attribute__((ext_vector_type(4)));
// ext_vector (no ctors) makes AS4 deref legal; uniform addr -> s_load
typedef const f4 __attribute__((address_space(4))) * c4as;
typedef const f2 __attribute__((address_space(4))) * c2as;

__device__ __forceinline__ float wave_reduce(float v) {
#pragma unroll
    for (int o = 32; o > 0; o >>= 1) v += __shfl_down(v, o);
    return v;
}

// d' = c^2 - 2 p.c  — shared by scan & comb so results are bitwise identical.
__device__ __forceinline__ f2 dprime(f2 cx, f2 cy, f2 nn, f2 m2x, f2 m2y) {
    return __builtin_elementwise_fma(cx, m2x, __builtin_elementwise_fma(cy, m2y, nn));
}

// signed-float bits -> order-preserving unsigned key (d' can be negative)
__device__ __forceinline__ unsigned fkey(float f) {
    unsigned u = __float_as_uint(f);
    return u ^ (0x80000000u | (unsigned)((int)u >> 31));
}
__device__ __forceinline__ float fkey_inv(unsigned k) {
    return __uint_as_float((k & 0x80000000u) ? (k ^ 0x80000000u) : ~k);
}

// =================== K0: interp table (+ norms) + g2p ===================
// blocks 0..31: tabP[b*2560+q]=(x0,x1,y0,y1), tabN=(n0,n1), n=fmaf(y,y,x*x)
// blocks 32..95: gt -> nearest pred (round-6-proven body) -> gsum/msum
__global__ __launch_bounds__(THR) void k_pre(
    const float* __restrict__ gt, const float* __restrict__ pred0,
    const float* __restrict__ pred1, const float* __restrict__ mask,
    float* __restrict__ tabP, float* __restrict__ tabN,
    float* __restrict__ gsum, float* __restrict__ msum) {
    const int bid = blockIdx.x, tid = threadIdx.x;
    if (bid < BATCH) {
        const float* gtb = gt + bid * NG * 2;
#pragma unroll
        for (int i = 0; i < NPAIR_B / THR; ++i) {       // 10 pairs/thread, coalesced
            int q = i * THR + tid;
            int k0 = 2 * q, k1 = 2 * q + 1;
            int j0 = k0 / TSTEP, t0 = k0 - j0 * TSTEP;
            int j1 = k1 / TSTEP, t1 = k1 - j1 * TSTEP;
            int jm0 = (j0 + NG - 1) & (NG - 1), jm1 = (j1 + NG - 1) & (NG - 1);
            float tf0 = (float)t0 / 10.0f, uf0 = 1.0f - tf0;  // same bits as rounds 1-10
            float tf1 = (float)t1 / 10.0f, uf1 = 1.0f - tf1;
            float x0 = fmaf(gtb[2 * j0], tf0, gtb[2 * jm0] * uf0);
            float y0 = fmaf(gtb[2 * j0 + 1], tf0, gtb[2 * jm0 + 1] * uf0);
            float x1 = fmaf(gtb[2 * j1], tf1, gtb[2 * jm1] * uf1);
            float y1 = fmaf(gtb[2 * j1 + 1], tf1, gtb[2 * jm1 + 1] * uf1);
            f4* tp = (f4*)tabP;
            f2* tn = (f2*)tabN;
            tp[bid * NPAIR_B + q] = (f4){x0, x1, y0, y1};
            tn[bid * NPAIR_B + q] = (f2){fmaf(y0, y0, x0 * x0), fmaf(y1, y1, x1 * x1)};
        }
    } else {
        __shared__ float2 sP[NP];
        __shared__ float swl[4], swm[4];
        const int gb = bid - BATCH;          // 0..63
        const int b = gb >> 1, gh = gb & 1;
        for (int k = tid; k < NP; k += THR)
            sP[k] = make_float2(pred0[(b * NP + k) * 2], pred0[(b * NP + k) * 2 + 1]);
        __syncthreads();

        const int g = gh * 256 + tid;
        const float gx = gt[(b * NG + g) * 2], gy = gt[(b * NG + g) * 2 + 1];
        float b0 = FLT_MAX, b1 = FLT_MAX;
        int i0 = 0, i1 = 0;
        const float4* s4 = (const float4*)sP;
#pragma unroll 4
        for (int i = 0; i < NP / 2; ++i) {
            float4 c = s4[i];
            float dx, dy, d;
            dx = gx - c.x; dy = gy - c.y; d = dx * dx + dy * dy;
            if (d < b0) { b0 = d; i0 = 2 * i; }
            dx = gx - c.z; dy = gy - c.w; d = dx * dx + dy * dy;
            if (d < b1) { b1 = d; i1 = 2 * i + 1; }
        }
        unsigned long long p0 = ((unsigned long long)__float_as_uint(b0) << 32) | (unsigned)i0;
        unsigned long long p1 = ((unsigned long long)__float_as_uint(b1) << 32) | (unsigned)i1;
        const int bi = (int)((p0 < p1 ? p0 : p1) & 0xFFFFFFFFull);
        const float m = mask[b * NG + g];
        float l = m * (fabsf(pred1[(b * NP + bi) * 2] - gx) +
                       fabsf(pred1[(b * NP + bi) * 2 + 1] - gy));
        float mm = 2.0f * m;
        l = wave_reduce(l);
        mm = wave_reduce(mm);
        if ((tid & 63) == 0) { swl[tid >> 6] = l; swm[tid >> 6] = mm; }
        __syncthreads();
        if (tid == 0) {
            gsum[gb] = swl[0] + swl[1] + swl[2] + swl[3];
            msum[gb] = swm[0] + swm[1] + swm[2] + swm[3];
        }
    }
}

// =================== K1: scan — scalar-pipe candidate delivery ===================
// 512 blocks x 256 thr. No LDS, no barriers. Candidates arrive via s_load
// (AS4 + wave-uniform address); hot loop = 3 pk-instr per pair per pred.
__global__ __launch_bounds__(THR) void k_scan(
    const float* __restrict__ pred0, const float* __restrict__ tabP,
    const float* __restrict__ tabN, unsigned long long* __restrict__ packs) {
    const int bid = blockIdx.x, tid = threadIdx.x;
    const int b = bid >> 4, ch = bid & (NCHUNK - 1);
    const c4as tp = (c4as)(unsigned long long)((const f4*)tabP + (size_t)b * NPAIR_B + ch * CH_PAIRS);
    const c2as tn = (c2as)(unsigned long long)((const f2*)tabN + (size_t)b * NPAIR_B + ch * CH_PAIRS);

    f2 M2X[RPT], M2Y[RPT];
#pragma unroll
    for (int r = 0; r < RPT; ++r) {
        const float2 p = *(const float2*)(pred0 + (b * NP + r * THR + tid) * 2);
        const float mx = -2.0f * p.x, my = -2.0f * p.y;
        M2X[r] = (f2){mx, mx};
        M2Y[r] = (f2){my, my};
    }

    float best[RPT];
    int btile[RPT];
#pragma unroll
    for (int r = 0; r < RPT; ++r) { best[r] = FLT_MAX; btile[r] = 0; }
#pragma unroll 1
    for (int t = 0; t < TILES_CH; ++t) {
        float acc[RPT];
#pragma unroll
        for (int r = 0; r < RPT; ++r) acc[r] = FLT_MAX;
#pragma unroll
        for (int q = 0; q < TILE_PAIRS; ++q) {
            const f4 c = tp[t * TILE_PAIRS + q];    // uniform addr -> s_load
            const f2 n = tn[t * TILE_PAIRS + q];
            const f2 cx = {c.x, c.y}, cy = {c.z, c.w};
#pragma unroll
            for (int r = 0; r < RPT; ++r) {
                f2 dd = dprime(cx, cy, n, M2X[r], M2Y[r]);
                acc[r] = fminf(fminf(dd.x, dd.y), acc[r]);   // v_min3
            }
        }
        const int tg = ch * TILES_CH + t;   // global tile id, ascending with chunk
#pragma unroll
        for (int r = 0; r < RPT; ++r)
            if (acc[r] < best[r]) { best[r] = acc[r]; btile[r] = tg; }   // strict <
    }
    // ordered-uint key (d' may be negative); tile in low bits -> u64 min = first-min tile
#pragma unroll
    for (int r = 0; r < RPT; ++r)
        packs[(size_t)ch * NPRED + b * NP + r * THR + tid] =
            ((unsigned long long)fkey(best[r]) << 32) | (unsigned)btile[r];
}

// =================== K2: fold + gather winning tile + L1 reduce ===================
// 64 blocks x 256 thr; thread = one pred point. Winning-tile values come
// straight from the table -> bitwise-guaranteed match.
__global__ __launch_bounds__(THR) void k_comb(
    const float* __restrict__ pred0, const float* __restrict__ pred1,
    const float* __restrict__ tabP, const float* __restrict__ tabN,
    const unsigned long long* __restrict__ packs, float* __restrict__ psum) {
    __shared__ float sw[4];
    const int tid = threadIdx.x;
    const int pr = blockIdx.x * THR + tid;
    const int b = pr >> 9;

    unsigned long long bp = packs[pr];
#pragma unroll
    for (int c = 1; c < NCHUNK; ++c) {
        unsigned long long v = packs[(size_t)c * NPRED + pr];
        if (v < bp) bp = v;
    }
    const float bestd = fkey_inv((unsigned)(bp >> 32));
    const int wt = (int)(bp & 0xFFFFFFFFull);

    const float2 p = *(const float2*)(pred0 + pr * 2);
    const float mx = -2.0f * p.x, my = -2.0f * p.y;
    const f2 m2x = {mx, mx}, m2y = {my, my};
    const f4* rp = (const f4*)tabP + (size_t)b * NPAIR_B + wt * TILE_PAIRS;
    const f2* rn = (const f2*)tabN + (size_t)b * NPAIR_B + wt * TILE_PAIRS;
    float nx = 0.f, ny = 0.f;
    bool found = false;
#pragma unroll
    for (int q = 0; q < TILE_PAIRS; ++q) {
        const f4 c = rp[q];          // per-lane divergent gather (identical values)
        const f2 n = rn[q];
        const f2 cx = {c.x, c.y}, cy = {c.z, c.w};
        f2 dd = dprime(cx, cy, n, m2x, m2y);
        bool m0 = (dd.x == bestd) && !found;
        nx = m0 ? c.x : nx; ny = m0 ? c.z : ny; found = found || m0;
        bool m1 = (dd.y == bestd) && !found;
        nx = m1 ? c.y : nx; ny = m1 ? c.w : ny; found = found || m1;
    }
    float s = fabsf(pred1[pr * 2] - nx) + fabsf(pred1[pr * 2 + 1] - ny);
    s = wave_reduce(s);
    if ((tid & 63) == 0) sw[tid >> 6] = s;
    __syncthreads();
    if (tid == 0) psum[blockIdx.x] = sw[0] + sw[1] + sw[2] + sw[3];
}

// =================== K3: final scalar (round-6-proven) ===================
__global__ __launch_bounds__(64) void k_final(
    const float* __restrict__ psum, const float* __restrict__ gsum,
    const float* __restrict__ msum, float* __restrict__ out) {
    const int t = threadIdx.x;
    float a = psum[t];
    float l = gsum[t];
    float m = msum[t];
    a = wave_reduce(a);
    l = wave_reduce(l);
    m = wave_reduce(m);
    if (t == 0)
        out[0] = (l / (m + 1.0f) + a / (float)(NPRED * 2)) * 0.5f;
}

extern "C" void kernel_launch(void* const* d_in, const int* in_sizes, int n_in,
                              void* d_out, int out_size, void* d_ws, size_t ws_size,
                              hipStream_t stream) {
    const float* pred0 = (const float*)d_in[0];   // ini_pred_poly [B,NP,2]
    const float* pred1 = (const float*)d_in[1];   // pred_polys_   [B,NP,2]
    const float* gt    = (const float*)d_in[2];   // gt_polys      [B,NG,2]
    const float* mask  = (const float*)d_in[3];   // keyPointsMask [B,NG]
    float* out = (float*)d_out;

    char* ws = (char*)d_ws;
    float* tabP = (float*)ws;                                     // 32*2560*16 = 1.3125 MB
    float* tabN = (float*)(ws + (size_t)BATCH * NPAIR_B * 16);    // 655 KB
    unsigned long long* packs =
        (unsigned long long*)(ws + (size_t)BATCH * NPAIR_B * 24); // 2 MB
    float* psum = (float*)(ws + (size_t)BATCH * NPAIR_B * 24 + (size_t)NCHUNK * NPRED * 8);
    float* gsum = psum + 64;
    float* msum = gsum + 64;

    hipLaunchKernelGGL(k_pre, dim3(BATCH + NB_G2P), dim3(THR), 0, stream,
                       gt, pred0, pred1, mask, tabP, tabN, gsum, msum);
    hipLaunchKernelGGL(k_scan, dim3(NB_SCAN), dim3(THR), 0, stream,
                       pred0, tabP, tabN, packs);
    hipLaunchKernelGGL(k_comb, dim3(NB_G2P), dim3(THR), 0, stream,
                       pred0, pred1, tabP, tabN, packs, psum);
    hipLaunchKernelGGL(k_final, dim3(1), dim3(64), 0, stream,
                       psum, gsum, msum, out);
}